// Round 8
// baseline (127.275 us; speedup 1.0000x reference)
//
#include <hip/hip_runtime.h>
#include <hip/hip_fp16.h>
#include <cstdint>
#include <cstddef>

// ---- problem constants ----
#define SEQ 2048
#define DM 1024
#define NH 16
#define NB 20

typedef _Float16 half8 __attribute__((ext_vector_type(8)));
typedef _Float16 half4 __attribute__((ext_vector_type(4)));
typedef _Float16 h2v __attribute__((ext_vector_type(2)));
typedef float f32x4 __attribute__((ext_vector_type(4)));
typedef int i32x4 __attribute__((ext_vector_type(4)));
typedef unsigned int u32;
typedef unsigned int u32x2 __attribute__((ext_vector_type(2)));

// ws layout (25,165,824 B total):
//  KF [2][16][64][2048] halves : per (b,h,kt): [k2][dh][lane][8]   (QK^T A-frags)
//  VF [2][16][64][2048] halves : per (b,h,kt): [k2][dtp][lane][8]  (PV B-frags)
//  PB [2][64][65536] bytes     : per (b,qblk32): [kt][lane][qs][k2][4] bucket*4|sentinel80
#define KF_HALVES 4194304
#define VF_HALVES 4194304

// =================== prepass: fragment-order everything (unchanged) ===================
__global__ __launch_bounds__(256) void pa_prep(
    const float* __restrict__ v, const float* __restrict__ k,
    const int* __restrict__ diff, const int* __restrict__ mask,
    _Float16* __restrict__ KF, _Float16* __restrict__ VF,
    unsigned char* __restrict__ PB) {
  const int bid = blockIdx.x, tid = threadIdx.x;
  if (bid < 2048) {
    int img = bid >> 4;                    // 0..127 = b*64+kt
    int bb = img >> 6, kt = img & 63;
    int tix = ((bid & 15) << 8) | tid;     // 0..4095
    int r = tix >> 7;                      // row in tile 0..31 (= k2*16+l16)
    int c0 = (tix & 127) << 3;             // col 0..1016
    const float* src = k + ((size_t)(bb * SEQ + kt * 32 + r)) * DM + c0;
    f32x4 a = *(const f32x4*)src;
    f32x4 c = *(const f32x4*)(src + 4);
    half8 o = {(_Float16)a[0], (_Float16)a[1], (_Float16)a[2], (_Float16)a[3],
               (_Float16)c[0], (_Float16)c[1], (_Float16)c[2], (_Float16)c[3]};
    int h = c0 >> 6, dh = (c0 >> 5) & 1, g4 = (c0 >> 3) & 3;
    int k2 = r >> 4, l16 = r & 15;
    int lane = g4 * 16 + l16;
    size_t off = ((size_t)((bb * 16 + h) * 64 + kt)) * 2048 + (k2 * 2 + dh) * 512 + lane * 8;
    *(half8*)(KF + off) = o;
  } else if (bid < 3072) {
    int b3 = bid - 2048;
    int img = b3 >> 3;                     // 0..127
    int bb = img >> 6, kt = img & 63;
    int tix = ((b3 & 7) << 8) | tid;       // 0..2047
    int kq = tix >> 8;                     // 0..7
    int k2 = kq >> 2, g4 = kq & 3;
    int d0 = (tix & 255) << 2;             // 0..1020
    const float* src = v + ((size_t)(bb * SEQ + kt * 32 + k2 * 16 + g4 * 4)) * DM + d0;
    f32x4 m0 = *(const f32x4*)(src);
    f32x4 m1 = *(const f32x4*)(src + DM);
    f32x4 m2 = *(const f32x4*)(src + 2 * DM);
    f32x4 m3 = *(const f32x4*)(src + 3 * DM);
#pragma unroll
    for (int i = 0; i < 4; ++i) {
      int d = d0 + i;
      int l16 = d & 15, dt = (d >> 4) & 3, dtp = dt >> 1, w = dt & 1, h = d >> 6;
      int lane = g4 * 16 + l16;
      half4 o = {(_Float16)m0[i], (_Float16)m1[i], (_Float16)m2[i], (_Float16)m3[i]};
      size_t off = ((size_t)((bb * 16 + h) * 64 + kt)) * 2048 + (k2 * 2 + dtp) * 512 + lane * 8 + w * 4;
      *(half4*)(VF + off) = o;
    }
  } else {
    int b4 = bid - 3072;                   // 0..4095
    int job = b4 >> 5;                     // 0..127 = b*64+qblk
    int bb = job >> 6, qblk = job & 63;
    int tix = ((b4 & 31) << 8) | tid;      // 0..8191
    int kt = tix >> 7;
    int rem = tix & 127;
    int g4 = rem & 3, l16 = (rem >> 2) & 15, qs = rem >> 6;
    int lane = g4 * 16 + l16;
    int qrow = qblk * 32 + qs * 16 + l16;
    size_t rowbase = ((size_t)(bb * SEQ + qrow)) * SEQ;
    u32x2 wds;
#pragma unroll
    for (int k2 = 0; k2 < 2; ++k2) {
      int kk = kt * 32 + k2 * 16 + g4 * 4;
      i32x4 dv = *(const i32x4*)(diff + rowbase + kk);
      i32x4 mv = *(const i32x4*)(mask + rowbase + kk);
      u32 wd = 0;
#pragma unroll
      for (int r = 0; r < 4; ++r) {
        u32 byte = mv[r] ? ((u32)dv[r] << 2) : 80u;  // bucket*4; 80 = masked sentinel lane 20
        wd |= byte << (8 * r);
      }
      wds[k2] = wd;
    }
    size_t off = ((size_t)job) * 65536 + (size_t)kt * 1024 + (size_t)lane * 16 + (size_t)qs * 8;
    *(u32x2*)(PB + off) = wds;
  }
}

// packed-f16 silu, bias already inside s (added via MFMA C-operand in f32)
__device__ __forceinline__ half4 silu4nb(const f32x4& s) {
  h2v x01 = __builtin_bit_cast(h2v, __builtin_amdgcn_cvt_pkrtz(s[0], s[1]));
  h2v x23 = __builtin_bit_cast(h2v, __builtin_amdgcn_cvt_pkrtz(s[2], s[3]));
  const h2v NL2E = {(_Float16)-1.44269504f, (_Float16)-1.44269504f};
  const h2v ONE = {(_Float16)1.0f, (_Float16)1.0f};
  h2v m01 = x01 * NL2E, m23 = x23 * NL2E;
  h2v e01 = __builtin_bit_cast(h2v, h2exp2(__builtin_bit_cast(__half2, m01)));
  h2v e23 = __builtin_bit_cast(h2v, h2exp2(__builtin_bit_cast(__half2, m23)));
  h2v d01 = e01 + ONE, d23 = e23 + ONE;
  h2v y01 = x01 * __builtin_bit_cast(h2v, h2rcp(__builtin_bit_cast(__half2, d01)));
  h2v y23 = x23 * __builtin_bit_cast(h2v, h2rcp(__builtin_bit_cast(__half2, d23)));
  return (half4){y01[0], y01[1], y23[0], y23[1]};
}

__device__ __forceinline__ f32x4 bias4(u32 u, int rbi) {
  f32x4 bb;
  bb[0] = __int_as_float(__builtin_amdgcn_ds_bpermute((int)(u & 0xffu), rbi));
  bb[1] = __int_as_float(__builtin_amdgcn_ds_bpermute((int)((u >> 8) & 0xffu), rbi));
  bb[2] = __int_as_float(__builtin_amdgcn_ds_bpermute((int)((u >> 16) & 0xffu), rbi));
  bb[3] = __int_as_float(__builtin_amdgcn_ds_bpermute((int)(u >> 24), rbi));
  return bb;
}

// =================== main: QB=64 per wave, bias-in-C, ksplit=4 ===================
// 1024 blocks x 256 thr (4 waves). Wave owns 64 q-rows x (512 k) x one head:
// 10 VMEM loads/iter serve 2x the compute of the old QB=32 (halved load:compute ratio).
// XCD (bid&7) owns one (b,ksp) combo: KF+VF 2MB + PB 1MB (disjoint kt-quarter) fits L2.
__global__ __launch_bounds__(256, 3) void pa_main(
    const _Float16* __restrict__ KF, const _Float16* __restrict__ VF,
    const unsigned char* __restrict__ PB, const float* __restrict__ q,
    const float* __restrict__ relbias, float* __restrict__ out) {
  const int tid = threadIdx.x, lane = tid & 63, wid = tid >> 6;
  const int l16 = lane & 15, g4 = lane >> 4;
  const int L = (blockIdx.x & 7) * 128 + (blockIdx.x >> 3);   // bijective, 8 XCDs x 128
  const int h = L & 15;
  const int qgrp = (L >> 4) & 7;
  const int ksp = (L >> 7) & 3;
  const int b = (L >> 9) & 1;
  const int qblk0 = (qgrp * 4 + wid) * 2;   // two adjacent 32-row q-blocks
  const int qbase = qblk0 * 32;             // 64 q rows

  const float rbv = (lane < NB) ? relbias[lane * NH + h] : -30000.0f;
  const int rbi = __float_as_int(rbv);

  // Q fragments, pre-scaled by 1/8: qs=0..3 spans 64 rows
  half8 qf[4][2];
#pragma unroll
  for (int qs = 0; qs < 4; ++qs)
#pragma unroll
    for (int dh = 0; dh < 2; ++dh) {
      const float* s = q + ((size_t)(b * SEQ + qbase + qs * 16 + l16)) * DM + h * 64 + dh * 32 + g4 * 8;
      f32x4 a = *(const f32x4*)s;
      f32x4 c = *(const f32x4*)(s + 4);
      qf[qs][dh] = {(_Float16)(a[0] * 0.125f), (_Float16)(a[1] * 0.125f),
                    (_Float16)(a[2] * 0.125f), (_Float16)(a[3] * 0.125f),
                    (_Float16)(c[0] * 0.125f), (_Float16)(c[1] * 0.125f),
                    (_Float16)(c[2] * 0.125f), (_Float16)(c[3] * 0.125f)};
    }

  f32x4 acc[4][4];
#pragma unroll
  for (int qs = 0; qs < 4; ++qs)
#pragma unroll
    for (int dt = 0; dt < 4; ++dt) acc[qs][dt] = (f32x4){0.f, 0.f, 0.f, 0.f};

  const _Float16* kfb = KF + ((size_t)((b * 16 + h) * 64 + ksp * 16)) * 2048 + lane * 8;
  const _Float16* vfb = VF + ((size_t)((b * 16 + h) * 64 + ksp * 16)) * 2048 + lane * 8;
  const unsigned char* pbbA = PB + ((size_t)(b * 64 + qblk0)) * 65536 + (size_t)(ksp * 16) * 1024 + lane * 16;
  const unsigned char* pbbB = pbbA + 65536;

#pragma unroll 2
  for (int t = 0; t < 16; ++t) {
    half8 kfr[4], vvr[4];
#pragma unroll
    for (int j = 0; j < 4; ++j) {
      kfr[j] = *(const half8*)(kfb + (size_t)t * 2048 + j * 512);
      vvr[j] = *(const half8*)(vfb + (size_t)t * 2048 + j * 512);
    }
    i32x4 pqA = *(const i32x4*)(pbbA + (size_t)t * 1024);
    i32x4 pqB = *(const i32x4*)(pbbB + (size_t)t * 1024);

#pragma unroll
    for (int k2 = 0; k2 < 2; ++k2) {
      half4 pf[4];
#pragma unroll
      for (int qs = 0; qs < 4; ++qs) {
        u32 u = (u32)((qs < 2 ? pqA : pqB)[(qs & 1) * 2 + k2]);
        f32x4 bb = bias4(u, rbi);   // C-operand init: bias layout == D layout
        f32x4 sa = __builtin_amdgcn_mfma_f32_16x16x32_f16(kfr[k2 * 2 + 0], qf[qs][0], bb, 0, 0, 0);
        sa = __builtin_amdgcn_mfma_f32_16x16x32_f16(kfr[k2 * 2 + 1], qf[qs][1], sa, 0, 0, 0);
        pf[qs] = silu4nb(sa);
      }
      half4 vf0 = __builtin_shufflevector(vvr[k2 * 2 + 0], vvr[k2 * 2 + 0], 0, 1, 2, 3);
      half4 vf1 = __builtin_shufflevector(vvr[k2 * 2 + 0], vvr[k2 * 2 + 0], 4, 5, 6, 7);
      half4 vf2 = __builtin_shufflevector(vvr[k2 * 2 + 1], vvr[k2 * 2 + 1], 0, 1, 2, 3);
      half4 vf3 = __builtin_shufflevector(vvr[k2 * 2 + 1], vvr[k2 * 2 + 1], 4, 5, 6, 7);
#pragma unroll
      for (int qs = 0; qs < 4; ++qs) {
        acc[qs][0] = __builtin_amdgcn_mfma_f32_16x16x16f16(pf[qs], vf0, acc[qs][0], 0, 0, 0);
        acc[qs][1] = __builtin_amdgcn_mfma_f32_16x16x16f16(pf[qs], vf1, acc[qs][1], 0, 0, 0);
        acc[qs][2] = __builtin_amdgcn_mfma_f32_16x16x16f16(pf[qs], vf2, acc[qs][2], 0, 0, 0);
        acc[qs][3] = __builtin_amdgcn_mfma_f32_16x16x16f16(pf[qs], vf3, acc[qs][3], 0, 0, 0);
      }
    }
  }

  // epilogue: ksplit=4 partials -> atomicAdd into zeroed out
#pragma unroll
  for (int qs = 0; qs < 4; ++qs)
#pragma unroll
    for (int dt = 0; dt < 4; ++dt)
#pragma unroll
      for (int r = 0; r < 4; ++r) {
        int qrow = qbase + qs * 16 + g4 * 4 + r;
        int d = h * 64 + dt * 16 + l16;
        atomicAdd(&out[((size_t)(b * SEQ) + qrow) * DM + d], acc[qs][dt][r]);
      }
}

extern "C" void kernel_launch(void* const* d_in, const int* in_sizes, int n_in,
                              void* d_out, int out_size, void* d_ws, size_t ws_size,
                              hipStream_t stream) {
  const float* v = (const float*)d_in[0];
  const float* k = (const float*)d_in[1];
  const float* q = (const float*)d_in[2];
  const int* mask = (const int*)d_in[3];
  const int* diff = (const int*)d_in[4];
  const float* relbias = (const float*)d_in[5];
  float* out = (float*)d_out;

  _Float16* KF = (_Float16*)d_ws;
  _Float16* VF = KF + KF_HALVES;
  unsigned char* PB = (unsigned char*)(VF + VF_HALVES);
  if (ws_size < (size_t)25165824) return;

  (void)hipMemsetAsync(d_out, 0, (size_t)out_size * sizeof(float), stream);
  pa_prep<<<7168, 256, 0, stream>>>(v, k, diff, mask, KF, VF, PB);
  pa_main<<<1024, 256, 0, stream>>>(KF, VF, PB, q, relbias, out);
}

// Round 9
// 104.963 us; speedup vs baseline: 1.2126x; 1.2126x over previous
//
#include <hip/hip_runtime.h>
#include <hip/hip_fp16.h>
#include <cstdint>
#include <cstddef>

// ---- problem constants ----
#define SEQ 2048
#define DM 1024
#define NH 16
#define NB 20

typedef _Float16 half8 __attribute__((ext_vector_type(8)));
typedef _Float16 half4 __attribute__((ext_vector_type(4)));
typedef _Float16 h2v __attribute__((ext_vector_type(2)));
typedef float f32x4 __attribute__((ext_vector_type(4)));
typedef int i32x4 __attribute__((ext_vector_type(4)));
typedef unsigned int u32;
typedef unsigned int u32x2 __attribute__((ext_vector_type(2)));

// ws layout (25,165,824 B total):
//  KF [2][16][64][2048] halves : per (b,h,kt): [k2][dh][lane][8]   (QK^T A-frags)
//  VF [2][16][64][2048] halves : per (b,h,kt): [k2][dtp][lane][8]  (PV B-frags)
//  PB [2][64][65536] bytes     : per (b,qblk32): [kt][lane][qs][k2][4] bucket*4|sentinel80
#define KF_HALVES 4194304
#define VF_HALVES 4194304

// =================== prepass: fragment-order everything (unchanged) ===================
__global__ __launch_bounds__(256) void pa_prep(
    const float* __restrict__ v, const float* __restrict__ k,
    const int* __restrict__ diff, const int* __restrict__ mask,
    _Float16* __restrict__ KF, _Float16* __restrict__ VF,
    unsigned char* __restrict__ PB) {
  const int bid = blockIdx.x, tid = threadIdx.x;
  if (bid < 2048) {
    int img = bid >> 4;                    // 0..127 = b*64+kt
    int bb = img >> 6, kt = img & 63;
    int tix = ((bid & 15) << 8) | tid;     // 0..4095
    int r = tix >> 7;                      // row in tile 0..31 (= k2*16+l16)
    int c0 = (tix & 127) << 3;             // col 0..1016
    const float* src = k + ((size_t)(bb * SEQ + kt * 32 + r)) * DM + c0;
    f32x4 a = *(const f32x4*)src;
    f32x4 c = *(const f32x4*)(src + 4);
    half8 o = {(_Float16)a[0], (_Float16)a[1], (_Float16)a[2], (_Float16)a[3],
               (_Float16)c[0], (_Float16)c[1], (_Float16)c[2], (_Float16)c[3]};
    int h = c0 >> 6, dh = (c0 >> 5) & 1, g4 = (c0 >> 3) & 3;
    int k2 = r >> 4, l16 = r & 15;
    int lane = g4 * 16 + l16;
    size_t off = ((size_t)((bb * 16 + h) * 64 + kt)) * 2048 + (k2 * 2 + dh) * 512 + lane * 8;
    *(half8*)(KF + off) = o;
  } else if (bid < 3072) {
    int b3 = bid - 2048;
    int img = b3 >> 3;                     // 0..127
    int bb = img >> 6, kt = img & 63;
    int tix = ((b3 & 7) << 8) | tid;       // 0..2047
    int kq = tix >> 8;                     // 0..7
    int k2 = kq >> 2, g4 = kq & 3;
    int d0 = (tix & 255) << 2;             // 0..1020
    const float* src = v + ((size_t)(bb * SEQ + kt * 32 + k2 * 16 + g4 * 4)) * DM + d0;
    f32x4 m0 = *(const f32x4*)(src);
    f32x4 m1 = *(const f32x4*)(src + DM);
    f32x4 m2 = *(const f32x4*)(src + 2 * DM);
    f32x4 m3 = *(const f32x4*)(src + 3 * DM);
#pragma unroll
    for (int i = 0; i < 4; ++i) {
      int d = d0 + i;
      int l16 = d & 15, dt = (d >> 4) & 3, dtp = dt >> 1, w = dt & 1, h = d >> 6;
      int lane = g4 * 16 + l16;
      half4 o = {(_Float16)m0[i], (_Float16)m1[i], (_Float16)m2[i], (_Float16)m3[i]};
      size_t off = ((size_t)((bb * 16 + h) * 64 + kt)) * 2048 + (k2 * 2 + dtp) * 512 + lane * 8 + w * 4;
      *(half4*)(VF + off) = o;
    }
  } else {
    int b4 = bid - 3072;                   // 0..4095
    int job = b4 >> 5;                     // 0..127 = b*64+qblk
    int bb = job >> 6, qblk = job & 63;
    int tix = ((b4 & 31) << 8) | tid;      // 0..8191
    int kt = tix >> 7;
    int rem = tix & 127;
    int g4 = rem & 3, l16 = (rem >> 2) & 15, qs = rem >> 6;
    int lane = g4 * 16 + l16;
    int qrow = qblk * 32 + qs * 16 + l16;
    size_t rowbase = ((size_t)(bb * SEQ + qrow)) * SEQ;
    u32x2 wds;
#pragma unroll
    for (int k2 = 0; k2 < 2; ++k2) {
      int kk = kt * 32 + k2 * 16 + g4 * 4;
      i32x4 dv = *(const i32x4*)(diff + rowbase + kk);
      i32x4 mv = *(const i32x4*)(mask + rowbase + kk);
      u32 wd = 0;
#pragma unroll
      for (int r = 0; r < 4; ++r) {
        u32 byte = mv[r] ? ((u32)dv[r] << 2) : 80u;  // bucket*4; 80 = masked sentinel lane 20
        wd |= byte << (8 * r);
      }
      wds[k2] = wd;
    }
    size_t off = ((size_t)job) * 65536 + (size_t)kt * 1024 + (size_t)lane * 16 + (size_t)qs * 8;
    *(u32x2*)(PB + off) = wds;
  }
}

// packed-f16 silu with pre-gathered f16 bias pairs
__device__ __forceinline__ half4 silu4b(const f32x4& s, h2v b01, h2v b23) {
  h2v x01 = __builtin_bit_cast(h2v, __builtin_amdgcn_cvt_pkrtz(s[0], s[1])) + b01;
  h2v x23 = __builtin_bit_cast(h2v, __builtin_amdgcn_cvt_pkrtz(s[2], s[3])) + b23;
  const h2v NL2E = {(_Float16)-1.44269504f, (_Float16)-1.44269504f};
  const h2v ONE = {(_Float16)1.0f, (_Float16)1.0f};
  h2v m01 = x01 * NL2E, m23 = x23 * NL2E;
  h2v e01 = __builtin_bit_cast(h2v, h2exp2(__builtin_bit_cast(__half2, m01)));
  h2v e23 = __builtin_bit_cast(h2v, h2exp2(__builtin_bit_cast(__half2, m23)));
  h2v d01 = e01 + ONE, d23 = e23 + ONE;
  h2v y01 = x01 * __builtin_bit_cast(h2v, h2rcp(__builtin_bit_cast(__half2, d01)));
  h2v y23 = x23 * __builtin_bit_cast(h2v, h2rcp(__builtin_bit_cast(__half2, d23)));
  return (half4){y01[0], y01[1], y23[0], y23[1]};
}

struct BiasSet { h2v b[2][2][2]; };  // [qs][k2][pair]

__device__ __forceinline__ void gather_bias(BiasSet& bs, const i32x4& pq, int rbi) {
#pragma unroll
  for (int qs = 0; qs < 2; ++qs)
#pragma unroll
    for (int k2 = 0; k2 < 2; ++k2) {
      u32 u = (u32)pq[qs * 2 + k2];
      float b0 = __int_as_float(__builtin_amdgcn_ds_bpermute((int)(u & 0xffu), rbi));
      float b1 = __int_as_float(__builtin_amdgcn_ds_bpermute((int)((u >> 8) & 0xffu), rbi));
      float b2 = __int_as_float(__builtin_amdgcn_ds_bpermute((int)((u >> 16) & 0xffu), rbi));
      float b3 = __int_as_float(__builtin_amdgcn_ds_bpermute((int)(u >> 24), rbi));
      bs.b[qs][k2][0] = __builtin_bit_cast(h2v, __builtin_amdgcn_cvt_pkrtz(b0, b1));
      bs.b[qs][k2][1] = __builtin_bit_cast(h2v, __builtin_amdgcn_cvt_pkrtz(b2, b3));
    }
}

__device__ __forceinline__ void compute_tile(
    const half8 (&kfr)[4], const half8 (&vvr)[4], const BiasSet& bs,
    const half8 (&qf)[2][2], f32x4 (&acc)[2][4]) {
  const f32x4 zf = {0.f, 0.f, 0.f, 0.f};
#pragma unroll
  for (int k2 = 0; k2 < 2; ++k2) {
    f32x4 sa[2];
#pragma unroll
    for (int qs = 0; qs < 2; ++qs) {
      sa[qs] = __builtin_amdgcn_mfma_f32_16x16x32_f16(kfr[k2 * 2 + 0], qf[qs][0], zf, 0, 0, 0);
      sa[qs] = __builtin_amdgcn_mfma_f32_16x16x32_f16(kfr[k2 * 2 + 1], qf[qs][1], sa[qs], 0, 0, 0);
    }
    half4 pf[2];
    pf[0] = silu4b(sa[0], bs.b[0][k2][0], bs.b[0][k2][1]);
    pf[1] = silu4b(sa[1], bs.b[1][k2][0], bs.b[1][k2][1]);

    half4 vf0 = __builtin_shufflevector(vvr[k2 * 2 + 0], vvr[k2 * 2 + 0], 0, 1, 2, 3);
    half4 vf1 = __builtin_shufflevector(vvr[k2 * 2 + 0], vvr[k2 * 2 + 0], 4, 5, 6, 7);
    half4 vf2 = __builtin_shufflevector(vvr[k2 * 2 + 1], vvr[k2 * 2 + 1], 0, 1, 2, 3);
    half4 vf3 = __builtin_shufflevector(vvr[k2 * 2 + 1], vvr[k2 * 2 + 1], 4, 5, 6, 7);
#pragma unroll
    for (int qs = 0; qs < 2; ++qs) {
      acc[qs][0] = __builtin_amdgcn_mfma_f32_16x16x16f16(pf[qs], vf0, acc[qs][0], 0, 0, 0);
      acc[qs][1] = __builtin_amdgcn_mfma_f32_16x16x16f16(pf[qs], vf1, acc[qs][1], 0, 0, 0);
      acc[qs][2] = __builtin_amdgcn_mfma_f32_16x16x16f16(pf[qs], vf2, acc[qs][2], 0, 0, 0);
      acc[qs][3] = __builtin_amdgcn_mfma_f32_16x16x16f16(pf[qs], vf3, acc[qs][3], 0, 0, 0);
    }
  }
}

// =================== main: sched_barrier-pinned 2-deep pipeline ===================
// R4 config (1024 blocks x 256 thr, QB=32, ksplit=2). Per half-iter: issue 9 loads for
// t+1/t+2, sched_barrier(0) PINS them before compute (R7's pipeline collapsed because
// the allocator sank loads into the consumer — VGPR stayed 60). Bias gathered a phase
// early so bpermute latency hides under compute. launch_bounds(256,3): 168-VGPR cap.
__global__ __launch_bounds__(256, 3) void pa_main(
    const _Float16* __restrict__ KF, const _Float16* __restrict__ VF,
    const unsigned char* __restrict__ PB, const float* __restrict__ q,
    const float* __restrict__ relbias, float* __restrict__ out) {
  const int tid = threadIdx.x, lane = tid & 63, wid = tid >> 6;
  const int l16 = lane & 15, g4 = lane >> 4;
  const int L = (blockIdx.x & 7) * 128 + (blockIdx.x >> 3);   // bijective, 8 XCDs x 128
  const int h = L & 15;
  const int qgrp = (L >> 4) & 15;
  const int ksp = (L >> 8) & 1;
  const int b = L >> 9;
  const int qblk = qgrp * 4 + wid;
  const int qbase = qblk * 32;

  const float rbv = (lane < NB) ? relbias[lane * NH + h] : -30000.0f;
  const int rbi = __float_as_int(rbv);

  half8 qf[2][2];
#pragma unroll
  for (int qs = 0; qs < 2; ++qs)
#pragma unroll
    for (int dh = 0; dh < 2; ++dh) {
      const float* s = q + ((size_t)(b * SEQ + qbase + qs * 16 + l16)) * DM + h * 64 + dh * 32 + g4 * 8;
      f32x4 a = *(const f32x4*)s;
      f32x4 c = *(const f32x4*)(s + 4);
      qf[qs][dh] = {(_Float16)(a[0] * 0.125f), (_Float16)(a[1] * 0.125f),
                    (_Float16)(a[2] * 0.125f), (_Float16)(a[3] * 0.125f),
                    (_Float16)(c[0] * 0.125f), (_Float16)(c[1] * 0.125f),
                    (_Float16)(c[2] * 0.125f), (_Float16)(c[3] * 0.125f)};
    }

  f32x4 acc[2][4];
#pragma unroll
  for (int qs = 0; qs < 2; ++qs)
#pragma unroll
    for (int dt = 0; dt < 4; ++dt) acc[qs][dt] = (f32x4){0.f, 0.f, 0.f, 0.f};

  const _Float16* kfb = KF + ((size_t)((b * 16 + h) * 64 + ksp * 32)) * 2048 + lane * 8;
  const _Float16* vfb = VF + ((size_t)((b * 16 + h) * 64 + ksp * 32)) * 2048 + lane * 8;
  const unsigned char* pbb = PB + ((size_t)(b * 64 + qblk)) * 65536 + (size_t)(ksp * 32) * 1024 + lane * 16;

#define LOADKV(T, KR, VR)                                              \
  do {                                                                 \
    _Pragma("unroll") for (int j = 0; j < 4; ++j) {                    \
      KR[j] = *(const half8*)(kfb + (size_t)(T) * 2048 + j * 512);     \
      VR[j] = *(const half8*)(vfb + (size_t)(T) * 2048 + j * 512);     \
    }                                                                  \
  } while (0)
#define CLMP(T) ((T) < 32 ? (T) : 31)

  half8 kA[4], vA[4], kB[4], vB[4];
  i32x4 pq1, pqX;
  BiasSet biasA, biasB;

  // prologue: tile0 K/V + bias(0); pq(1) in flight
  LOADKV(0, kA, vA);
  {
    i32x4 pqP = *(const i32x4*)(pbb);
    gather_bias(biasA, pqP, rbi);
  }
  pq1 = *(const i32x4*)(pbb + 1024);

  for (int t = 0; t < 32; t += 2) {
    // even phase: compute t; prefetch K/V(t+1), pq(t+2); gather bias(t+1)
    LOADKV(t + 1, kB, vB);
    pqX = *(const i32x4*)(pbb + (size_t)CLMP(t + 2) * 1024);
    __builtin_amdgcn_sched_barrier(0);
    gather_bias(biasB, pq1, rbi);
    compute_tile(kA, vA, biasA, qf, acc);
    // odd phase: compute t+1; prefetch K/V(t+2), pq(t+3); gather bias(t+2)
    LOADKV(CLMP(t + 2), kA, vA);
    pq1 = *(const i32x4*)(pbb + (size_t)CLMP(t + 3) * 1024);
    __builtin_amdgcn_sched_barrier(0);
    gather_bias(biasA, pqX, rbi);
    compute_tile(kB, vB, biasB, qf, acc);
  }
#undef LOADKV
#undef CLMP

  // epilogue: ksplit=2 partials -> atomicAdd into zeroed out
#pragma unroll
  for (int qs = 0; qs < 2; ++qs)
#pragma unroll
    for (int dt = 0; dt < 4; ++dt)
#pragma unroll
      for (int r = 0; r < 4; ++r) {
        int qrow = qbase + qs * 16 + g4 * 4 + r;
        int d = h * 64 + dt * 16 + l16;
        atomicAdd(&out[((size_t)(b * SEQ) + qrow) * DM + d], acc[qs][dt][r]);
      }
}

extern "C" void kernel_launch(void* const* d_in, const int* in_sizes, int n_in,
                              void* d_out, int out_size, void* d_ws, size_t ws_size,
                              hipStream_t stream) {
  const float* v = (const float*)d_in[0];
  const float* k = (const float*)d_in[1];
  const float* q = (const float*)d_in[2];
  const int* mask = (const int*)d_in[3];
  const int* diff = (const int*)d_in[4];
  const float* relbias = (const float*)d_in[5];
  float* out = (float*)d_out;

  _Float16* KF = (_Float16*)d_ws;
  _Float16* VF = KF + KF_HALVES;
  unsigned char* PB = (unsigned char*)(VF + VF_HALVES);
  if (ws_size < (size_t)25165824) return;

  (void)hipMemsetAsync(d_out, 0, (size_t)out_size * sizeof(float), stream);
  pa_prep<<<7168, 256, 0, stream>>>(v, k, diff, mask, KF, VF, PB);
  pa_main<<<1024, 256, 0, stream>>>(KF, VF, PB, q, relbias, out);
}